// Round 1
// baseline (103.593 us; speedup 1.0000x reference)
//
#include <hip/hip_runtime.h>
#include <math.h>

// DepthawareConv: B=4, Cin=32, H=W=256, Cout=32, 3x3, pad=1
// out[b,o,h,w] = sum_c sum_ij x_pad[b,c,h+i-1,w+j-1]
//                * exp(-8.3*|d[b,h,w] - d_pad[b,h+i-1,w+j-1]|) * W[o,c,i,j]

#define ALPHA_F 8.3f

constexpr int B_    = 4;
constexpr int CIN   = 32;
constexpr int COUT  = 32;
constexpr int H_    = 256;
constexpr int W_    = 256;
constexpr int KTAPS = 9;

// Transpose weight (O, C, 3, 3) -> wt[(c*9+ij)*COUT + o] so the inner
// o-loop reads 32 contiguous floats at a wave-uniform address (s_load).
__global__ void transpose_w_kernel(const float* __restrict__ w,
                                   float* __restrict__ wt) {
    int idx = blockIdx.x * 256 + threadIdx.x;
    if (idx >= COUT * CIN * KTAPS) return;
    int o = idx / (CIN * KTAPS);
    int k = idx - o * (CIN * KTAPS); // c*9 + ij
    wt[k * COUT + o] = w[idx];
}

template <bool TR>
__global__ __launch_bounds__(256)
void dconv_kernel(const float* __restrict__ x,
                  const float* __restrict__ depth,
                  const float* __restrict__ wgt,  // TR ? wt[(c*9+ij)*32+o] : w[(o*32+c)*9+ij]
                  float* __restrict__ out) {
    // block = one (b,h) row; thread = w coordinate
    const int w  = threadIdx.x;
    const int bh = blockIdx.x;
    const int b  = bh >> 8;   // / H_
    const int h  = bh & 255;  // % H_

    const float* dplane = depth + b * (H_ * W_);
    const float  dc     = dplane[h * W_ + w];

    float acc[COUT];
#pragma unroll
    for (int o = 0; o < COUT; ++o) acc[o] = 0.f;

    const float* xb = x + b * (CIN * H_ * W_);

    // Runtime tap loops (keeps code size ~10KB/tap inside I$);
    // c and o loops fully unrolled with static indexing.
    for (int i = 0; i < 3; ++i) {
        const int  hh  = h + i - 1;
        const bool okh = ((unsigned)hh < (unsigned)H_);
        for (int j = 0; j < 3; ++j) {
            const int  ww = w + j - 1;
            const bool ok = okh && ((unsigned)ww < (unsigned)W_);
            const int  ij = i * 3 + j;

            // similarity for this tap (channel-independent)
            const float dp = ok ? dplane[hh * W_ + ww] : 0.f;
            const float s  = __expf(-ALPHA_F * fabsf(dc - dp));

            // preload the 32 input-channel values for this tap
            float xv[CIN];
            const int base = hh * W_ + ww;
#pragma unroll
            for (int c = 0; c < CIN; ++c) {
                xv[c] = ok ? xb[c * (H_ * W_) + base] : 0.f;
            }

#pragma unroll
            for (int c = 0; c < CIN; ++c) {
                const float v = xv[c] * s;
                if (TR) {
                    const float* wr = wgt + (c * KTAPS + ij) * COUT;
#pragma unroll
                    for (int o = 0; o < COUT; ++o) {
                        acc[o] = fmaf(v, wr[o], acc[o]);
                    }
                } else {
#pragma unroll
                    for (int o = 0; o < COUT; ++o) {
                        acc[o] = fmaf(v, wgt[(o * CIN + c) * KTAPS + ij], acc[o]);
                    }
                }
            }
        }
    }

    float* ob = out + (b * COUT * H_ + h) * W_ + w;
#pragma unroll
    for (int o = 0; o < COUT; ++o) {
        ob[o * (H_ * W_)] = acc[o];
    }
}

extern "C" void kernel_launch(void* const* d_in, const int* in_sizes, int n_in,
                              void* d_out, int out_size, void* d_ws, size_t ws_size,
                              hipStream_t stream) {
    const float* x     = (const float*)d_in[0];
    const float* depth = (const float*)d_in[1];
    const float* wgt   = (const float*)d_in[2];
    float*       out   = (float*)d_out;

    const int nblocks = B_ * H_; // 1024 blocks, 256 threads each

    if (ws_size >= (size_t)(COUT * CIN * KTAPS) * sizeof(float)) {
        float* wt = (float*)d_ws;
        transpose_w_kernel<<<(COUT * CIN * KTAPS + 255) / 256, 256, 0, stream>>>(wgt, wt);
        dconv_kernel<true><<<nblocks, 256, 0, stream>>>(x, depth, wt, out);
    } else {
        dconv_kernel<false><<<nblocks, 256, 0, stream>>>(x, depth, wgt, out);
    }
}

// Round 2
// 42.472 us; speedup vs baseline: 2.4391x; 2.4391x over previous
//
#include <hip/hip_runtime.h>
#include <hip/hip_bf16.h>
#include <math.h>

// DepthawareConv as bf16 MFMA GEMM:
//   out[o, pix] = sum_{ij, c} W[o, c, ij] * x[c, pix+off(ij)] * sim(ij, pix)
// K ordered tap-major (k = ij*32 + c) so each 16x16x32 MFMA chunk = one tap,
// letting sim (channel-independent) fold into the B fragment as one scalar.

#define ALPHA_F 8.3f

constexpr int B_    = 4;
constexpr int CIN   = 32;
constexpr int COUT  = 32;
constexpr int H_    = 256;
constexpr int W_    = 256;
constexpr int KTAPS = 9;
constexpr int HW    = H_ * W_;

typedef __attribute__((ext_vector_type(8))) short bf16x8;
typedef __attribute__((ext_vector_type(4))) float f32x4;

static __device__ __forceinline__ short f2bf(float f) {
    __hip_bfloat16 h = __float2bfloat16(f);
    return __builtin_bit_cast(short, h);
}

// Pack weights into per-lane A-fragment layout (bf16):
// wf[((ij*2 + t)*64 + lane)*8 + e] = W[o = t*16 + (lane&15), c = (lane>>4)*8 + e, ij]
// A-frag layout for mfma_f32_16x16x32_bf16 (verified m89):
//   row m = lane&15, k = (lane>>4)*8 + e
__global__ void prep_wfrag(const float* __restrict__ w, short* __restrict__ wf) {
    int idx = blockIdx.x * 256 + threadIdx.x;
    if (idx >= KTAPS * 2 * 64 * 8) return;
    int e  = idx & 7;
    int l  = (idx >> 3) & 63;
    int t  = (idx >> 9) & 1;
    int ij = idx >> 10;
    int o  = t * 16 + (l & 15);
    int c  = (l >> 4) * 8 + e;
    wf[idx] = f2bf(w[(o * CIN + c) * KTAPS + ij]);
}

__global__ __launch_bounds__(256)
void dconv_mfma(const float* __restrict__ x,
                const float* __restrict__ depth,
                const short* __restrict__ wf,
                float* __restrict__ out) {
    // XCD-aware swizzle: 4096 blocks, 4096 % 8 == 0 -> bijective chunked map
    const int bid  = (int)blockIdx.x;
    const int bswz = (bid & 7) * 512 + (bid >> 3);

    const int lane = threadIdx.x & 63;
    const int tile = bswz * 4 + (threadIdx.x >> 6); // 16 pixels per wave
    const int p0   = tile << 4;

    const int b  = p0 >> 16;        // HW = 65536 pixels per image
    const int h  = (p0 >> 8) & 255;
    const int n  = lane & 15;       // pixel within tile (B-frag col)
    const int wp = (p0 & 255) + n;  // w coordinate
    const int cg = (lane >> 4) * 8; // channel group (B-frag k base)

    const float* xb  = x + b * (CIN * HW);
    const float* dpl = depth + b * HW;
    const int    pix = h * W_ + wp;
    const float  dc  = dpl[pix];

    const bf16x8* wfv = (const bf16x8*)wf;

    f32x4 acc0 = {0.f, 0.f, 0.f, 0.f};
    f32x4 acc1 = {0.f, 0.f, 0.f, 0.f};

#pragma unroll
    for (int ij = 0; ij < KTAPS; ++ij) {
        const int di = ij / 3 - 1;
        const int dj = ij % 3 - 1;
        const bool ok = ((unsigned)(h + di) < (unsigned)H_) &&
                        ((unsigned)(wp + dj) < (unsigned)W_);
        const int  off = ok ? (di * W_ + dj) : 0;   // safe addr when !ok
        const float dp = dpl[pix + off];
        const float s  = ok ? __expf(-ALPHA_F * fabsf(dc - dp)) : 0.f;

        bf16x8 bfrag;
#pragma unroll
        for (int e = 0; e < 8; ++e) {
            bfrag[e] = f2bf(xb[(cg + e) * HW + (pix + off)] * s);
        }

        const bf16x8 a0 = wfv[(ij * 2 + 0) * 64 + lane];
        const bf16x8 a1 = wfv[(ij * 2 + 1) * 64 + lane];
        acc0 = __builtin_amdgcn_mfma_f32_16x16x32_bf16(a0, bfrag, acc0, 0, 0, 0);
        acc1 = __builtin_amdgcn_mfma_f32_16x16x32_bf16(a1, bfrag, acc1, 0, 0, 0);
    }

    // C/D layout: col(pixel) = lane&15, row(o') = (lane>>4)*4 + reg
    float*    ob   = out + b * (COUT * HW) + pix;
    const int orow = (lane >> 4) * 4;
#pragma unroll
    for (int j = 0; j < 4; ++j) {
        ob[(orow + j) * HW]      = acc0[j];
        ob[(orow + j + 16) * HW] = acc1[j];
    }
}

// ---------- fp32 fallback (previous kernel, weights untransposed) ----------
__global__ __launch_bounds__(256)
void dconv_fallback(const float* __restrict__ x,
                    const float* __restrict__ depth,
                    const float* __restrict__ wgt,
                    float* __restrict__ out) {
    const int w  = threadIdx.x;
    const int bh = blockIdx.x;
    const int b  = bh >> 8;
    const int h  = bh & 255;

    const float* dplane = depth + b * HW;
    const float  dc     = dplane[h * W_ + w];

    float acc[COUT];
#pragma unroll
    for (int o = 0; o < COUT; ++o) acc[o] = 0.f;

    const float* xb = x + b * (CIN * HW);

    for (int i = 0; i < 3; ++i) {
        const int  hh  = h + i - 1;
        const bool okh = ((unsigned)hh < (unsigned)H_);
        for (int j = 0; j < 3; ++j) {
            const int  ww = w + j - 1;
            const bool ok = okh && ((unsigned)ww < (unsigned)W_);
            const int  ij = i * 3 + j;
            const float dp = ok ? dplane[hh * W_ + ww] : 0.f;
            const float s  = __expf(-ALPHA_F * fabsf(dc - dp));
            const int base = hh * W_ + ww;
#pragma unroll
            for (int c = 0; c < CIN; ++c) {
                const float v = (ok ? xb[c * HW + base] : 0.f) * s;
#pragma unroll
                for (int o = 0; o < COUT; ++o) {
                    acc[o] = fmaf(v, wgt[(o * CIN + c) * KTAPS + ij], acc[o]);
                }
            }
        }
    }

    float* ob = out + (b * COUT * H_ + h) * W_ + w;
#pragma unroll
    for (int o = 0; o < COUT; ++o) ob[o * HW] = acc[o];
}

extern "C" void kernel_launch(void* const* d_in, const int* in_sizes, int n_in,
                              void* d_out, int out_size, void* d_ws, size_t ws_size,
                              hipStream_t stream) {
    const float* x     = (const float*)d_in[0];
    const float* depth = (const float*)d_in[1];
    const float* wgt   = (const float*)d_in[2];
    float*       out   = (float*)d_out;

    const size_t wf_bytes = (size_t)(KTAPS * 2 * 64 * 8) * sizeof(short); // 18 KB

    if (ws_size >= wf_bytes) {
        short* wf = (short*)d_ws;
        prep_wfrag<<<(KTAPS * 2 * 64 * 8 + 255) / 256, 256, 0, stream>>>(wgt, wf);
        // 262144 pixels / 16 per wave = 16384 waves; 4 waves/block -> 4096 blocks
        dconv_mfma<<<4096, 256, 0, stream>>>(x, depth, wf, out);
    } else {
        dconv_fallback<<<B_ * H_, 256, 0, stream>>>(x, depth, wgt, out);
    }
}